// Round 7
// baseline (288.762 us; speedup 1.0000x reference)
//
#include <hip/hip_runtime.h>
#include <math.h>

// MeanShift: x (2,3,96,96) fp32, 5 iters of all-pairs Gaussian-weighted mean.
// Round-4 proven multi-kernel structure; exp replaced by fast bit-trick exp2.
//
// Scaled space: s = sqrt(50*log2e) -> w = exp2(u), u = 2p.y - |p|^2 - |y|^2
//             = -|p-y|^2 in [-3s^2, 0] = [-216.4, 0].
// LDS stages (2px,2py,2pz,-|p|^2); ypar stores PLAIN (y0,y1,y2, BIAS-|y|^2)
// -- NOT 2y: rounds 5/6 stored 2y giving u=4p.y-..., t up to ~650, V > INT_MAX,
// cvt_i32 saturates to 0x7FFFFFFF == NaN-as-float. That was the NaN bug.
//
// BIAS = 217 > 3s^2 -> t = u+217 in [0.6, 217]; V = 2^23*(t + f(1-f)(a+b*f)),
// f = fract(t), a = ln2-1, b = -(2ln2-1)-a; w = as_float((int)V) = 2^(u+90)
// within ~0.06%. Uniform 2^90 cancels in num/den; den<=2^103, num<=2^108: safe.

typedef float v2f __attribute__((ext_vector_type(2)));

#define NPTS   9216            // 96*96
#define NB     2
#define TOT    (NB * NPTS)     // 18432
#define MSPLIT 24              // m-slices per n-tile
#define SLICE  (NPTS / MSPLIT) // 384 m per block
#define WSLICE (SLICE / 4)     // 96 m per wave
#define NPB    256             // n per block (4 per thread)
#define NTILES (NPTS / NPB)    // 36
#define LOG2E  1.44269504088896340736f
#define BIASF  217.0f          // > 3*s^2 = 216.4 -> t always positive
#define T23F   8388608.0f      // 2^23
#define A2F    -2574068.3f     // (ln2-1)        * 2^23
#define B2F    -666404.1f      // (a+b=1-2ln2)   -> b = -0.07944154; b*2^23

__device__ __forceinline__ v2f splat2(float v) { return (v2f){v, v}; }

// acc[t][gid] = float4(num0,num1,num2,den), t=0..4, pre-zeroed, atomic-combined.

__global__ __launch_bounds__(256, 4) void ms_iter(const float* __restrict__ x,
                                                  const float4* __restrict__ accIn,
                                                  float4* __restrict__ accOut,
                                                  float s, int first) {
    __shared__ float4 smem[1024];               // 16 KB
    float* const xs = (float*)smem;             // [SLICE] 2*px
    float* const ys = xs + SLICE;               // 2*py
    float* const zs = ys + SLICE;               // 2*pz
    float* const ws = zs + SLICE;               // -|p|^2
    float4* const ypar = smem + SLICE;          // [NPB] (y0,y1,y2, BIAS-|y|^2)
    float4* const red  = smem;                  // [4][NPB] overlay (post-loop)

    const int tid  = threadIdx.x;
    const int lane = tid & 63;
    const int wv   = tid >> 6;
    const int k    = blockIdx.x % MSPLIT;
    const int tile = blockIdx.x / MSPLIT;
    const int b    = tile / NTILES;
    const int nt   = tile - b * NTILES;
    const int nbase = nt * NPB;
    const float* xb = x + b * 3 * NPTS;
    const int mbeg = k * SLICE;

    // SoA staging, scaled, 2x folded into coords.
    for (int i = tid; i < SLICE; i += 256) {
        int g = mbeg + i;
        float px = xb[g] * s;
        float py = xb[NPTS + g] * s;
        float pz = xb[2 * NPTS + g] * s;
        xs[i] = 2.f * px;
        ys[i] = 2.f * py;
        zs[i] = 2.f * pz;
        ws[i] = -fmaf(px, px, fmaf(py, py, pz * pz));
    }
    // y for this iteration (scaled space). PLAIN y here (2x lives in LDS!).
    {
        float y0, y1, y2;
        if (first) {
            int n = nbase + tid;
            y0 = xb[n] * s; y1 = xb[NPTS + n] * s; y2 = xb[2 * NPTS + n] * s;
        } else {
            float4 a = accIn[b * NPTS + nbase + tid];
            float inv = 1.0f / a.w;
            y0 = a.x * inv; y1 = a.y * inv; y2 = a.z * inv;
        }
        ypar[tid] = make_float4(y0, y1, y2,
                                BIASF - fmaf(y0, y0, fmaf(y1, y1, y2 * y2)));
    }
    __syncthreads();

    v2f Yx[4], Yy[4], Yz[4], Yw[4], Ax[4], Ay[4], Az[4], Aw[4];
#pragma unroll
    for (int j = 0; j < 4; ++j) {
        float4 yp = ypar[lane + 64 * j];
        Yx[j] = splat2(yp.x); Yy[j] = splat2(yp.y);
        Yz[j] = splat2(yp.z); Yw[j] = splat2(yp.w);
        Ax[j] = splat2(0.f); Ay[j] = splat2(0.f);
        Az[j] = splat2(0.f); Aw[j] = splat2(0.f);
    }

    const float* xsw = xs + wv * WSLICE;
    const float* ysw = ys + wv * WSLICE;
    const float* zsw = zs + wv * WSLICE;
    const float* wsw = ws + wv * WSLICE;

    const v2f T23 = splat2(T23F);
    const v2f A2  = splat2(A2F);
    const v2f B2  = splat2(B2F);

    for (int i = 0; i < WSLICE; i += 4) {       // 4 m per superiter
        float4 PX = *(const float4*)(xsw + i);
        float4 PY = *(const float4*)(ysw + i);
        float4 PZ = *(const float4*)(zsw + i);
        float4 PW = *(const float4*)(wsw + i);
        v2f px0 = (v2f){PX.x, PX.y}, px1 = (v2f){PX.z, PX.w};
        v2f py0 = (v2f){PY.x, PY.y}, py1 = (v2f){PY.z, PY.w};
        v2f pz0 = (v2f){PZ.x, PZ.y}, pz1 = (v2f){PZ.z, PZ.w};
        v2f pw0 = (v2f){PW.x, PW.y}, pw1 = (v2f){PW.z, PW.w};
#pragma unroll
        for (int j = 0; j < 4; ++j) {
            // t = 2p.y - |p|^2 + (BIAS - |y|^2) = BIAS - |p-y|^2  in [0.6, 217]
            v2f t0 = pw0 + Yw[j];
            t0 = __builtin_elementwise_fma(pz0, Yz[j], t0);
            t0 = __builtin_elementwise_fma(py0, Yy[j], t0);
            t0 = __builtin_elementwise_fma(px0, Yx[j], t0);
            v2f t1 = pw1 + Yw[j];
            t1 = __builtin_elementwise_fma(pz1, Yz[j], t1);
            t1 = __builtin_elementwise_fma(py1, Yy[j], t1);
            t1 = __builtin_elementwise_fma(px1, Yx[j], t1);
            v2f f0, f1;
            f0.x = __builtin_amdgcn_fractf(t0.x);
            f0.y = __builtin_amdgcn_fractf(t0.y);
            f1.x = __builtin_amdgcn_fractf(t1.x);
            f1.y = __builtin_amdgcn_fractf(t1.y);
            v2f h0 = __builtin_elementwise_fma(-f0, f0, f0);  // f*(1-f)
            v2f h1 = __builtin_elementwise_fma(-f1, f1, f1);
            v2f c0 = __builtin_elementwise_fma(f0, B2, A2);   // (a + b*f)*2^23
            v2f c1 = __builtin_elementwise_fma(f1, B2, A2);
            v2f g0 = h0 * c0;
            v2f g1 = h1 * c1;
            v2f V0 = __builtin_elementwise_fma(t0, T23, g0);
            v2f V1 = __builtin_elementwise_fma(t1, T23, g1);
            v2f w0, w1;
            w0.x = __int_as_float((int)V0.x);
            w0.y = __int_as_float((int)V0.y);
            w1.x = __int_as_float((int)V1.x);
            w1.y = __int_as_float((int)V1.y);
            Ax[j] = __builtin_elementwise_fma(w0, px0, Ax[j]);
            Ay[j] = __builtin_elementwise_fma(w0, py0, Ay[j]);
            Az[j] = __builtin_elementwise_fma(w0, pz0, Az[j]);
            Aw[j] += w0;
            Ax[j] = __builtin_elementwise_fma(w1, px1, Ax[j]);
            Ay[j] = __builtin_elementwise_fma(w1, py1, Ay[j]);
            Az[j] = __builtin_elementwise_fma(w1, pz1, Az[j]);
            Aw[j] += w1;
        }
    }

    // Cross-wave reduction (red overlays staging; staging dead now).
    __syncthreads();
#pragma unroll
    for (int j = 0; j < 4; ++j) {
        red[wv * NPB + lane + 64 * j] =
            make_float4(Ax[j].x + Ax[j].y, Ay[j].x + Ay[j].y,
                        Az[j].x + Az[j].y, Aw[j].x + Aw[j].y);
    }
    __syncthreads();
    {
        float4 r0 = red[tid];
        float4 r1 = red[NPB + tid];
        float4 r2 = red[2 * NPB + tid];
        float4 r3 = red[3 * NPB + tid];
        // coords were accumulated with the 2x fold -> scale by 0.5
        float ox = 0.5f * ((r0.x + r1.x) + (r2.x + r3.x));
        float oy = 0.5f * ((r0.y + r1.y) + (r2.y + r3.y));
        float oz = 0.5f * ((r0.z + r1.z) + (r2.z + r3.z));
        float od = (r0.w + r1.w) + (r2.w + r3.w);
        float* dst = (float*)&accOut[b * NPTS + nbase + tid];
        atomicAdd(dst + 0, ox);
        atomicAdd(dst + 1, oy);
        atomicAdd(dst + 2, oz);
        atomicAdd(dst + 3, od);
    }
}

__global__ __launch_bounds__(256) void ms_pack(const float4* __restrict__ acc4,
                                               float* __restrict__ out,
                                               float invs) {
    int gid = blockIdx.x * 256 + threadIdx.x;
    int b = gid / NPTS;
    int n = gid - b * NPTS;
    float4 a = acc4[gid];
    float f = invs / a.w;                       // unscale + normalize
    float* ob = out + b * 3 * NPTS;
    ob[n]            = a.x * f;
    ob[NPTS + n]     = a.y * f;
    ob[2 * NPTS + n] = a.z * f;
}

extern "C" void kernel_launch(void* const* d_in, const int* in_sizes, int n_in,
                              void* d_out, int out_size, void* d_ws, size_t ws_size,
                              hipStream_t stream) {
    const float* x = (const float*)d_in[0];
    float* out = (float*)d_out;
    float s = sqrtf(50.0f * LOG2E);                 // 8.4932...

    float4* acc = (float4*)d_ws;                    // 5 * TOT * 16 B = 1.47 MB

    // Zero all 5 accumulator buffers (atomic targets) in one async memset.
    hipMemsetAsync(acc, 0, (size_t)5 * TOT * sizeof(float4), stream);

    for (int it = 0; it < 5; ++it) {
        const float4* accIn = (it == 0) ? nullptr : acc + (size_t)(it - 1) * TOT;
        ms_iter<<<NB * NTILES * MSPLIT, 256, 0, stream>>>(
            x, accIn, acc + (size_t)it * TOT, s, it == 0 ? 1 : 0);
    }
    ms_pack<<<TOT / 256, 256, 0, stream>>>(acc + (size_t)4 * TOT, out, 1.0f / s);
}

// Round 8
// 236.325 us; speedup vs baseline: 1.2219x; 1.2219x over previous
//
#include <hip/hip_runtime.h>
#include <math.h>

// MeanShift: x (2,3,96,96) fp32, 5 iters of all-pairs Gaussian-weighted mean.
// Round-4 proven hot loop (hw v_exp_f32 + v2f pk-fma, 390 cyc/superiter
// measured) + LDS prefetch + MSPLIT=32 for residency.
//
// Scaled space: s = sqrt(50*log2e) -> w = exp2(u), u = 2p.y - |p|^2 - |y|^2.
// LDS stages (2px,2py,2pz,-|p|^2); ypar stores PLAIN (y0,y1,y2,-|y|^2)
// (the 2x lives in LDS -- storing 2y was rounds 5/6's NaN bug).

typedef float v2f __attribute__((ext_vector_type(2)));

#define NPTS   9216            // 96*96
#define NB     2
#define TOT    (NB * NPTS)     // 18432
#define MSPLIT 32              // m-slices per n-tile
#define SLICE  (NPTS / MSPLIT) // 288 m per block
#define WSLICE (SLICE / 4)     // 72 m per wave
#define NPB    256             // n per block (4 per thread)
#define NTILES (NPTS / NPB)    // 36
#define LOG2E  1.44269504088896340736f

__device__ __forceinline__ v2f splat2(float v) { return (v2f){v, v}; }

// acc[t][gid] = float4(num0,num1,num2,den), t=0..4, pre-zeroed, atomic-combined.

__global__ __launch_bounds__(256, 4) void ms_iter(const float* __restrict__ x,
                                                  const float4* __restrict__ accIn,
                                                  float4* __restrict__ accOut,
                                                  float s, int first) {
    __shared__ float4 smem[1024];               // 16 KB
    float* const xs = (float*)smem;             // [SLICE] 2*px
    float* const ys = xs + SLICE;               // 2*py
    float* const zs = ys + SLICE;               // 2*pz
    float* const ws = zs + SLICE;               // -|p|^2
    float4* const ypar = smem + SLICE;          // [NPB] (y0,y1,y2,-|y|^2)
    float4* const red  = smem;                  // [4][NPB] overlay (post-loop)

    const int tid  = threadIdx.x;
    const int lane = tid & 63;
    const int wv   = tid >> 6;
    const int k    = blockIdx.x % MSPLIT;
    const int tile = blockIdx.x / MSPLIT;
    const int b    = tile / NTILES;
    const int nt   = tile - b * NTILES;
    const int nbase = nt * NPB;
    const float* xb = x + b * 3 * NPTS;
    const int mbeg = k * SLICE;

    // SoA staging, scaled, 2x folded into coords.
    for (int i = tid; i < SLICE; i += 256) {
        int g = mbeg + i;
        float px = xb[g] * s;
        float py = xb[NPTS + g] * s;
        float pz = xb[2 * NPTS + g] * s;
        xs[i] = 2.f * px;
        ys[i] = 2.f * py;
        zs[i] = 2.f * pz;
        ws[i] = -fmaf(px, px, fmaf(py, py, pz * pz));
    }
    // y for this iteration (scaled space). PLAIN y (2x lives in LDS).
    {
        float y0, y1, y2;
        if (first) {
            int n = nbase + tid;
            y0 = xb[n] * s; y1 = xb[NPTS + n] * s; y2 = xb[2 * NPTS + n] * s;
        } else {
            float4 a = accIn[b * NPTS + nbase + tid];
            float inv = 1.0f / a.w;
            y0 = a.x * inv; y1 = a.y * inv; y2 = a.z * inv;
        }
        ypar[tid] = make_float4(y0, y1, y2,
                                -fmaf(y0, y0, fmaf(y1, y1, y2 * y2)));
    }
    __syncthreads();

    v2f Yx[4], Yy[4], Yz[4], Yw[4], Ax[4], Ay[4], Az[4], Aw[4];
#pragma unroll
    for (int j = 0; j < 4; ++j) {
        float4 yp = ypar[lane + 64 * j];
        Yx[j] = splat2(yp.x); Yy[j] = splat2(yp.y);
        Yz[j] = splat2(yp.z); Yw[j] = splat2(yp.w);
        Ax[j] = splat2(0.f); Ay[j] = splat2(0.f);
        Az[j] = splat2(0.f); Aw[j] = splat2(0.f);
    }

    const float* xsw = xs + wv * WSLICE;
    const float* ysw = ys + wv * WSLICE;
    const float* zsw = zs + wv * WSLICE;
    const float* wsw = ws + wv * WSLICE;

    // Software-pipelined: prefetch superiter i+4 while computing on i.
    // Final prefetch (i+4 == WSLICE) reads the adjacent staging array's
    // start -- in-bounds of smem, never consumed.
    float4 PX = *(const float4*)(xsw);
    float4 PY = *(const float4*)(ysw);
    float4 PZ = *(const float4*)(zsw);
    float4 PW = *(const float4*)(wsw);
    for (int i = 0; i < WSLICE; i += 4) {       // 4 m per superiter
        float4 NX = *(const float4*)(xsw + i + 4);
        float4 NY = *(const float4*)(ysw + i + 4);
        float4 NZ = *(const float4*)(zsw + i + 4);
        float4 NW = *(const float4*)(wsw + i + 4);
        v2f px0 = (v2f){PX.x, PX.y}, px1 = (v2f){PX.z, PX.w};
        v2f py0 = (v2f){PY.x, PY.y}, py1 = (v2f){PY.z, PY.w};
        v2f pz0 = (v2f){PZ.x, PZ.y}, pz1 = (v2f){PZ.z, PZ.w};
        v2f pw0 = (v2f){PW.x, PW.y}, pw1 = (v2f){PW.z, PW.w};
#pragma unroll
        for (int j = 0; j < 4; ++j) {
            // u = 2p.y - |p|^2 - |y|^2 <= 0
            v2f t0 = pw0 + Yw[j];
            t0 = __builtin_elementwise_fma(pz0, Yz[j], t0);
            t0 = __builtin_elementwise_fma(py0, Yy[j], t0);
            t0 = __builtin_elementwise_fma(px0, Yx[j], t0);
            v2f t1 = pw1 + Yw[j];
            t1 = __builtin_elementwise_fma(pz1, Yz[j], t1);
            t1 = __builtin_elementwise_fma(py1, Yy[j], t1);
            t1 = __builtin_elementwise_fma(px1, Yx[j], t1);
            v2f w0, w1;
            w0.x = __builtin_amdgcn_exp2f(t0.x);
            w0.y = __builtin_amdgcn_exp2f(t0.y);
            w1.x = __builtin_amdgcn_exp2f(t1.x);
            w1.y = __builtin_amdgcn_exp2f(t1.y);
            Ax[j] = __builtin_elementwise_fma(w0, px0, Ax[j]);
            Ay[j] = __builtin_elementwise_fma(w0, py0, Ay[j]);
            Az[j] = __builtin_elementwise_fma(w0, pz0, Az[j]);
            Aw[j] += w0;
            Ax[j] = __builtin_elementwise_fma(w1, px1, Ax[j]);
            Ay[j] = __builtin_elementwise_fma(w1, py1, Ay[j]);
            Az[j] = __builtin_elementwise_fma(w1, pz1, Az[j]);
            Aw[j] += w1;
        }
        PX = NX; PY = NY; PZ = NZ; PW = NW;
    }

    // Cross-wave reduction (red overlays staging; staging dead now).
    __syncthreads();
#pragma unroll
    for (int j = 0; j < 4; ++j) {
        red[wv * NPB + lane + 64 * j] =
            make_float4(Ax[j].x + Ax[j].y, Ay[j].x + Ay[j].y,
                        Az[j].x + Az[j].y, Aw[j].x + Aw[j].y);
    }
    __syncthreads();
    {
        float4 r0 = red[tid];
        float4 r1 = red[NPB + tid];
        float4 r2 = red[2 * NPB + tid];
        float4 r3 = red[3 * NPB + tid];
        // coords were accumulated with the 2x fold -> scale by 0.5
        float ox = 0.5f * ((r0.x + r1.x) + (r2.x + r3.x));
        float oy = 0.5f * ((r0.y + r1.y) + (r2.y + r3.y));
        float oz = 0.5f * ((r0.z + r1.z) + (r2.z + r3.z));
        float od = (r0.w + r1.w) + (r2.w + r3.w);
        float* dst = (float*)&accOut[b * NPTS + nbase + tid];
        atomicAdd(dst + 0, ox);
        atomicAdd(dst + 1, oy);
        atomicAdd(dst + 2, oz);
        atomicAdd(dst + 3, od);
    }
}

__global__ __launch_bounds__(256) void ms_pack(const float4* __restrict__ acc4,
                                               float* __restrict__ out,
                                               float invs) {
    int gid = blockIdx.x * 256 + threadIdx.x;
    int b = gid / NPTS;
    int n = gid - b * NPTS;
    float4 a = acc4[gid];
    float f = invs / a.w;                       // unscale + normalize
    float* ob = out + b * 3 * NPTS;
    ob[n]            = a.x * f;
    ob[NPTS + n]     = a.y * f;
    ob[2 * NPTS + n] = a.z * f;
}

extern "C" void kernel_launch(void* const* d_in, const int* in_sizes, int n_in,
                              void* d_out, int out_size, void* d_ws, size_t ws_size,
                              hipStream_t stream) {
    const float* x = (const float*)d_in[0];
    float* out = (float*)d_out;
    float s = sqrtf(50.0f * LOG2E);                 // 8.4932...

    float4* acc = (float4*)d_ws;                    // 5 * TOT * 16 B = 1.47 MB

    // Zero all 5 accumulator buffers (atomic targets) in one async memset.
    hipMemsetAsync(acc, 0, (size_t)5 * TOT * sizeof(float4), stream);

    for (int it = 0; it < 5; ++it) {
        const float4* accIn = (it == 0) ? nullptr : acc + (size_t)(it - 1) * TOT;
        ms_iter<<<NB * NTILES * MSPLIT, 256, 0, stream>>>(
            x, accIn, acc + (size_t)it * TOT, s, it == 0 ? 1 : 0);
    }
    ms_pack<<<TOT / 256, 256, 0, stream>>>(acc + (size_t)4 * TOT, out, 1.0f / s);
}